// Round 12
// baseline (196.209 us; speedup 1.0000x reference)
//
#include <hip/hip_runtime.h>

// Problem constants (fixed by the reference setup)
constexpr int N_IN  = 50000;
constexpr int C     = 64;
constexpr int T     = 8;
constexpr int E     = 800000;
constexpr int N_OUT = 50000;
constexpr int F     = 64;

// Bin/sort parameters: one aggregate block == one bin of 64 output nodes.
constexpr int BINN   = 64;                           // nodes per bin
constexpr int NBIN   = (N_OUT + BINN - 1) / BINN;    // 782 (last bin: 16 nodes)
constexpr int CAP    = 1344;                         // padded slots per bin
// bin edges ~ Binomial(E, 64/50000): mean 1024, sigma 32 -> CAP = +10 sigma
constexpr int CHUNK  = 4096;                         // edges per binscatter block
constexpr int NCHUNK = (E + CHUNK - 1) / CHUNK;      // 196

// ---------------------------------------------------------------------------
// Workspace layout (bytes); total ~44.3 MB
// ---------------------------------------------------------------------------
constexpr size_t OFF_NFBF = 0;                       // bf16 [N_IN][64]    6.4 MB
constexpr size_t OFF_KT   = 6400000;                 // bf16 [64][512]     64 KB
constexpr size_t OFF_BCUR = OFF_KT + 65536;          // int [NBIN] (memset 0)
constexpr size_t OFF_ENT  = OFF_BCUR + 3200;         // u32 [NBIN*CAP]     4.2 MB
constexpr size_t OFF_BINW = OFF_ENT + 4204032;       // f32 [NBIN*CAP][8] 33.6 MB
static_assert(OFF_ENT % 16 == 0 && OFF_BINW % 16 == 0, "alignment");
static_assert((size_t)NBIN * CAP * 4 == 4204032, "ent size");

typedef __attribute__((ext_vector_type(8))) short short8;
typedef __attribute__((ext_vector_type(4))) float f32x4;

__device__ inline unsigned short f2bf(float x) {  // fp32 -> bf16, RNE
    unsigned int u = __float_as_uint(x);
    unsigned int r = (u + 0x7FFFu + ((u >> 16) & 1u)) >> 16;
    return (unsigned short)r;
}
__device__ inline float bf2f(unsigned short u) {
    return __uint_as_float(((unsigned int)u) << 16);
}

// ---------------------------------------------------------------------------
// Fused prep (ONE launch):
//   [0, 196)        binscatter: LDS bin-hist over the chunk, reserve runs via
//                   per-bin GLOBAL atomics (~300K total, 782 counters), append
//                   ent (4B: loc<<16|in) + binw (32B fp32, ef read coalesced)
//                   into each bin's padded window.
//   [196, 1759)     nf -> bf16
//   [1759, 1823)    K transpose
// ---------------------------------------------------------------------------
constexpr int BS_BLOCKS = NCHUNK;                       // 196
constexpr int NF_BLOCKS = (N_IN * C / 4 + 511) / 512;   // 1563
constexpr int KT_BLOCKS = T * C * F / 512;              // 64

__global__ __launch_bounds__(512) void fused_prep_kernel(
        const float* __restrict__ nf,
        const float* __restrict__ Kmat,
        const float* __restrict__ ef,
        const int* __restrict__ idx,
        unsigned short* __restrict__ nf_bf,
        unsigned short* __restrict__ K_T,
        int* __restrict__ bincur,
        unsigned* __restrict__ ent,
        float* __restrict__ binw) {
    __shared__ int hist[NBIN];
    __shared__ int cur[NBIN];

    const int b   = blockIdx.x;
    const int tid = threadIdx.x;

    if (b < BS_BLOCKS) {
        for (int i = tid; i < NBIN; i += 512) hist[i] = 0;
        __syncthreads();
        const int e0 = b * CHUNK;
        const int n  = min(CHUNK, E - e0);
        // pass 1: LDS histogram (idx read; re-read below is L2-hot)
        for (int i = tid; i < n; i += 512)
            atomicAdd(&hist[((const int2*)idx)[e0 + i].x >> 6], 1);
        __syncthreads();
        // reserve a contiguous run per non-empty bin (global atomics)
        for (int bb = tid; bb < NBIN; bb += 512) {
            int c = hist[bb];
            if (c > 0) cur[bb] = bb * CAP + atomicAdd(&bincur[bb], c);
        }
        __syncthreads();
        // pass 2: append into runs; weights read coalesced from ef
        for (int i = tid; i < n; i += 512) {
            int2 oi = ((const int2*)idx)[e0 + i];  // {out, in}, L2-hot
            int bin = oi.x >> 6;
            float w[8];
#pragma unroll
            for (int t = 0; t < T; ++t) w[t] = ef[(size_t)t * E + e0 + i];
            int pos = atomicAdd(&cur[bin], 1);
            if (pos < (bin + 1) * CAP) {  // overflow guard (P ~ 1e-20)
                ent[pos] = ((unsigned)(oi.x & 63) << 16) | (unsigned)oi.y;
                float4* dst = (float4*)(binw + (size_t)pos * 8);
                dst[0] = make_float4(w[0], w[1], w[2], w[3]);
                dst[1] = make_float4(w[4], w[5], w[6], w[7]);
            }
        }
    } else if (b < BS_BLOCKS + NF_BLOCKS) {
        int i = (b - BS_BLOCKS) * 512 + tid;  // float4 units
        if (i < N_IN * C / 4) {
            float4 v = ((const float4*)nf)[i];
            unsigned int u0 = (unsigned int)f2bf(v.x) | ((unsigned int)f2bf(v.y) << 16);
            unsigned int u1 = (unsigned int)f2bf(v.z) | ((unsigned int)f2bf(v.w) << 16);
            ((uint2*)nf_bf)[i] = make_uint2(u0, u1);
        }
    } else {
        int k = (b - BS_BLOCKS - NF_BLOCKS) * 512 + tid;  // 32768 exact
        int f = k & 63;
        int c = (k >> 6) & 63;
        int t = k >> 12;
        K_T[f * 512 + t * 64 + c] = f2bf(Kmat[k]);
    }
}

// ---------------------------------------------------------------------------
// aggbin: one block = one 64-node bin, 512 threads (8 waves), 4 blocks/CU.
//  Prologue (replaces the permfix KERNEL): bin-local counting sort entirely
//  in LDS -- 64-entry hist + scan + scatter into sent[CAP] (u32 rel<<16|in).
//  No ent2 array, no start[] array, no extra launch, no 6.4MB round-trip.
//  Then 2 groups of 32 nodes:
//   Phase 1 (per wave, 4 nodes, lane=c): entries via LDS broadcast reads;
//    4-edge unroll -> 4 independent 128B nf gathers in flight; weights via
//    wave-uniform scalar fp32 loads from binw[b*CAP+rel] (window-local).
//   Phase 2: 8 waves cover the 32x64 out tile (wave>>2 = row half,
//    wave&3 = 16-col f-tile); 16 chained mfma_f32_16x16x32_bf16 each.
// ---------------------------------------------------------------------------
__global__ __launch_bounds__(512) void aggbin_kernel(
        const unsigned short* __restrict__ nf_bf,
        const unsigned short* __restrict__ K_T,
        const int* __restrict__ bincur,
        const unsigned* __restrict__ ent,
        const float* __restrict__ binw,
        const float* __restrict__ bias,
        float* __restrict__ out) {
    __shared__ unsigned sent[CAP];             // 5.4 KB
    __shared__ unsigned short A_lds[32][520];  // 33.3 KB (+8 pad)
    __shared__ int hist[BINN];
    __shared__ int sstart[BINN + 1];
    __shared__ int cur[BINN];

    const int b    = blockIdx.x;
    const int tid  = threadIdx.x;
    const int wave = tid >> 6;
    const int lane = tid & 63;
    const int W0p  = b * CAP;
    const int cnt  = min(bincur[b], CAP);

    // ---- bin-local counting sort into LDS ----
    if (tid < BINN) hist[tid] = 0;
    __syncthreads();
    for (int i = tid; i < cnt; i += 512)
        atomicAdd(&hist[ent[W0p + i] >> 16], 1);
    __syncthreads();
    if (tid < BINN) sstart[tid] = hist[tid];
    __syncthreads();
    for (int off = 1; off < BINN; off <<= 1) {
        int x = 0;
        if (tid < BINN && tid >= off) x = sstart[tid - off];
        __syncthreads();
        if (tid < BINN && tid >= off) sstart[tid] += x;
        __syncthreads();
    }
    int excl = 0;
    if (tid < BINN) excl = sstart[tid] - hist[tid];
    __syncthreads();
    if (tid < BINN) { sstart[tid] = excl; cur[tid] = excl; }
    if (tid == 0) sstart[BINN] = cnt;
    __syncthreads();
    for (int i = tid; i < cnt; i += 512) {
        unsigned u = ent[W0p + i];  // L2-hot second read of a 5.4KB window
        int pos = atomicAdd(&cur[u >> 16], 1);
        sent[pos] = ((unsigned)i << 16) | (u & 0xFFFFu);  // rel | in
    }
    __syncthreads();

    const int mrow  = lane & 15;
    const int kb    = lane >> 4;
    const int fcol  = (wave & 3) * 16 + mrow;
    const int rbase = (wave >> 2) * 16;
    const float bv  = bias[fcol];

    for (int g = 0; g < 2; ++g) {
        // ---- Phase 1: 8 waves x 4 nodes = 32 nodes ----
        for (int q = 0; q < 4; ++q) {
            const int nl = g * 32 + wave * 4 + q;  // local node 0..63
            const int s0 = sstart[nl];
            const int s1 = sstart[nl + 1];

            float acc[8] = {0.f, 0.f, 0.f, 0.f, 0.f, 0.f, 0.f, 0.f};

            int j = s0;
            for (; j + 4 <= s1; j += 4) {
                const unsigned e0 = sent[j + 0];  // LDS broadcast reads
                const unsigned e1 = sent[j + 1];
                const unsigned e2 = sent[j + 2];
                const unsigned e3 = sent[j + 3];
                // 4 independent 128 B gathers in flight
                float x0 = bf2f(nf_bf[(size_t)(e0 & 0xFFFFu) * 64 + lane]);
                float x1 = bf2f(nf_bf[(size_t)(e1 & 0xFFFFu) * 64 + lane]);
                float x2 = bf2f(nf_bf[(size_t)(e2 & 0xFFFFu) * 64 + lane]);
                float x3 = bf2f(nf_bf[(size_t)(e3 & 0xFFFFu) * 64 + lane]);
                // wave-uniform scalar fp32 weight loads (bin-local window)
                const float* w0 = binw + ((size_t)W0p +
                    (unsigned)__builtin_amdgcn_readfirstlane((int)(e0 >> 16))) * 8;
                const float* w1 = binw + ((size_t)W0p +
                    (unsigned)__builtin_amdgcn_readfirstlane((int)(e1 >> 16))) * 8;
                const float* w2 = binw + ((size_t)W0p +
                    (unsigned)__builtin_amdgcn_readfirstlane((int)(e2 >> 16))) * 8;
                const float* w3 = binw + ((size_t)W0p +
                    (unsigned)__builtin_amdgcn_readfirstlane((int)(e3 >> 16))) * 8;
#pragma unroll
                for (int t = 0; t < T; ++t) {
                    acc[t] += w0[t] * x0;
                    acc[t] += w1[t] * x1;
                    acc[t] += w2[t] * x2;
                    acc[t] += w3[t] * x3;
                }
            }
            for (; j < s1; ++j) {
                const unsigned e0 = sent[j];
                float x0 = bf2f(nf_bf[(size_t)(e0 & 0xFFFFu) * 64 + lane]);
                const float* w0 = binw + ((size_t)W0p +
                    (unsigned)__builtin_amdgcn_readfirstlane((int)(e0 >> 16))) * 8;
#pragma unroll
                for (int t = 0; t < T; ++t) acc[t] += w0[t] * x0;
            }

#pragma unroll
            for (int t = 0; t < T; ++t)
                A_lds[wave * 4 + q][t * 64 + lane] = f2bf(acc[t]);
        }
        __syncthreads();

        // ---- Phase 2: MFMA epilogue (32x64 out tile, 8 waves) ----
        f32x4 acc4 = {0.f, 0.f, 0.f, 0.f};
#pragma unroll
        for (int s = 0; s < 16; ++s) {
            const int k0 = s * 32 + kb * 8;
            short8 a = *(const short8*)&A_lds[rbase + mrow][k0];
            short8 bm = *(const short8*)(K_T + (size_t)fcol * 512 + k0);
            acc4 = __builtin_amdgcn_mfma_f32_16x16x32_bf16(a, bm, acc4, 0, 0, 0);
        }
#pragma unroll
        for (int r = 0; r < 4; ++r) {
            const int orow = b * BINN + g * 32 + rbase + kb * 4 + r;
            if (orow < N_OUT)  // last bin has only 16 nodes
                out[(size_t)orow * F + fcol] = acc4[r] + bv;
        }
        __syncthreads();
    }
}

// ---------------------------------------------------------------------------
extern "C" void kernel_launch(void* const* d_in, const int* in_sizes, int n_in,
                              void* d_out, int out_size, void* d_ws, size_t ws_size,
                              hipStream_t stream) {
    const float* nf   = (const float*)d_in[0];  // (N_IN, C)
    const float* ef   = (const float*)d_in[1];  // (T, E)
    const int*   idx  = (const int*)d_in[2];    // (E, 2) int32 on device
    const float* Kmat = (const float*)d_in[3];  // (T, C, F)
    const float* bias = (const float*)d_in[4];  // (F,)
    float*       out  = (float*)d_out;          // (N_OUT, F)

    char* ws = (char*)d_ws;
    unsigned short* nf_bf  = (unsigned short*)(ws + OFF_NFBF);
    unsigned short* K_T    = (unsigned short*)(ws + OFF_KT);
    int*            bincur = (int*)(ws + OFF_BCUR);
    unsigned*       ent    = (unsigned*)(ws + OFF_ENT);
    float*          binw   = (float*)(ws + OFF_BINW);

    hipMemsetAsync(bincur, 0, NBIN * sizeof(int), stream);
    fused_prep_kernel<<<BS_BLOCKS + NF_BLOCKS + KT_BLOCKS, 512, 0, stream>>>(
        nf, Kmat, ef, idx, nf_bf, K_T, bincur, ent, binw);
    aggbin_kernel<<<NBIN, 512, 0, stream>>>(
        nf_bf, K_T, bincur, ent, binw, bias, out);
}

// Round 15
// 181.764 us; speedup vs baseline: 1.0795x; 1.0795x over previous
//
#include <hip/hip_runtime.h>

// Problem constants (fixed by the reference setup)
constexpr int N_IN  = 50000;
constexpr int C     = 64;
constexpr int T     = 8;
constexpr int E     = 800000;
constexpr int N_OUT = 50000;
constexpr int F     = 64;

// Reservation-based counting-sort parameters (R11 proven geometry)
constexpr int CHUNK  = 2048;                        // edges per binscatter block
constexpr int NCHUNK = (E + CHUNK - 1) / CHUNK;     // 391
constexpr int NBIN_S = (N_OUT + 255) / 256;         // 196 bins of 256 nodes
constexpr int CAP    = 5120;                        // padded slots per bin (+16 sigma)

// ---------------------------------------------------------------------------
// Workspace layout (bytes); total ~46.2 MB
// ---------------------------------------------------------------------------
constexpr size_t OFF_NFBF  = 0;                      // bf16 [N_IN][64]    6.4 MB
constexpr size_t OFF_KT    = 6400000;                // bf16 [64][512]     64 KB
constexpr size_t OFF_BCUR  = OFF_KT + 65536;         // int [NBIN_S] (memset 0)
constexpr size_t OFF_START = OFF_BCUR + 1024;        // int [N_OUT+1]
constexpr size_t OFF_ENT   = OFF_START + 200064;     // u32 [NBIN_S*CAP]   4.0 MB
constexpr size_t OFF_ENT2  = OFF_ENT + 4014080;      // u32 [E]            3.2 MB
constexpr size_t OFF_BINW  = OFF_ENT2 + 3200000;     // f32 [NBIN_S*CAP][8] 32.1 MB
static_assert(OFF_ENT % 16 == 0 && OFF_BINW % 16 == 0, "alignment");

typedef __attribute__((ext_vector_type(8))) short short8;
typedef __attribute__((ext_vector_type(4))) float f32x4;

__device__ inline unsigned short f2bf(float x) {  // fp32 -> bf16, RNE
    unsigned int u = __float_as_uint(x);
    unsigned int r = (u + 0x7FFFu + ((u >> 16) & 1u)) >> 16;
    return (unsigned short)r;
}
__device__ inline float bf2f(unsigned short u) {
    return __uint_as_float(((unsigned int)u) << 16);
}

// ---------------------------------------------------------------------------
// Fused prep (ONE launch):
//   [0, 391)        binscatter with LDS bin-GROUPING -> COALESCED run writes:
//                   pass1 hist -> scan -> reserve global runs; pass2 groups
//                   {ent-word, e-offset, bin} by bin in LDS; pass3 walks the
//                   grouped list so consecutive threads write consecutive
//                   ent/binw addresses (R11 had neighboring threads
//                   scattering 32B into different bins' runs).
//   [391, 1954)     nf -> bf16
//   [1954, 2018)    K transpose
// ---------------------------------------------------------------------------
constexpr int BS_BLOCKS = NCHUNK;                       // 391
constexpr int NF_BLOCKS = (N_IN * C / 4 + 511) / 512;   // 1563
constexpr int KT_BLOCKS = T * C * F / 512;              // 64

__global__ __launch_bounds__(512) void fused_prep_kernel(
        const float* __restrict__ nf,
        const float* __restrict__ Kmat,
        const float* __restrict__ ef,
        const int* __restrict__ idx,
        unsigned short* __restrict__ nf_bf,
        unsigned short* __restrict__ K_T,
        int* __restrict__ bincur,
        unsigned* __restrict__ ent,
        float* __restrict__ binw) {
    __shared__ int hist[NBIN_S];
    __shared__ int scb[NBIN_S];
    __shared__ int cur[NBIN_S];
    __shared__ int gdel[NBIN_S];
    __shared__ int sscan[256];
    __shared__ unsigned sgu[CHUNK];        // grouped ent words
    __shared__ unsigned short sge[CHUNK];  // grouped e-offsets
    __shared__ unsigned char sgb[CHUNK];   // grouped bin ids

    const int b   = blockIdx.x;
    const int tid = threadIdx.x;

    if (b < BS_BLOCKS) {
        for (int i = tid; i < NBIN_S; i += 512) hist[i] = 0;
        __syncthreads();
        const int e0 = b * CHUNK;
        const int n  = min(CHUNK, E - e0);
        // pass 1: histogram (coalesced idx read)
        for (int i = tid; i < n; i += 512)
            atomicAdd(&hist[((const int2*)idx)[e0 + i].x >> 8], 1);
        __syncthreads();
        // exclusive scan hist -> scb (196 < 256)
        if (tid < 256) sscan[tid] = (tid < NBIN_S) ? hist[tid] : 0;
        __syncthreads();
        for (int off = 1; off < 256; off <<= 1) {
            int x = 0;
            if (tid < 256 && tid >= off) x = sscan[tid - off];
            __syncthreads();
            if (tid < 256 && tid >= off) sscan[tid] += x;
            __syncthreads();
        }
        if (tid < NBIN_S) {
            int e = sscan[tid] - hist[tid];
            scb[tid] = e;
            cur[tid] = e;
        }
        __syncthreads();
        // reserve a contiguous global run per non-empty bin
        for (int bb = tid; bb < NBIN_S; bb += 512) {
            int c = hist[bb];
            if (c > 0)
                gdel[bb] = bb * CAP + atomicAdd(&bincur[bb], c) - scb[bb];
        }
        __syncthreads();
        // pass 2: group by bin in LDS (idx re-read is L2-hot)
        for (int i = tid; i < n; i += 512) {
            int2 oi = ((const int2*)idx)[e0 + i];
            int bin = oi.x >> 8;
            int r = atomicAdd(&cur[bin], 1);
            sgu[r] = ((unsigned)(oi.x & 255) << 16) | (unsigned)oi.y;
            sge[r] = (unsigned short)i;
            sgb[r] = (unsigned char)bin;
        }
        __syncthreads();
        // pass 3: coalesced run writes (consecutive i -> consecutive pos
        // within each run); ef read as within-chunk gather (L2-absorbed)
        for (int i = tid; i < n; i += 512) {
            int bin  = sgb[i];
            int pos  = gdel[bin] + i;
            if (pos < (bin + 1) * CAP) {  // overflow guard (P ~ 1e-20)
                int eoff = sge[i];
                float w[8];
#pragma unroll
                for (int t = 0; t < T; ++t) w[t] = ef[(size_t)t * E + e0 + eoff];
                ent[pos] = sgu[i];
                float4* dst = (float4*)(binw + (size_t)pos * 8);
                dst[0] = make_float4(w[0], w[1], w[2], w[3]);
                dst[1] = make_float4(w[4], w[5], w[6], w[7]);
            }
        }
    } else if (b < BS_BLOCKS + NF_BLOCKS) {
        int i = (b - BS_BLOCKS) * 512 + tid;  // float4 units
        if (i < N_IN * C / 4) {
            float4 v = ((const float4*)nf)[i];
            unsigned int u0 = (unsigned int)f2bf(v.x) | ((unsigned int)f2bf(v.y) << 16);
            unsigned int u1 = (unsigned int)f2bf(v.z) | ((unsigned int)f2bf(v.w) << 16);
            ((uint2*)nf_bf)[i] = make_uint2(u0, u1);
        }
    } else {
        int k = (b - BS_BLOCKS - NF_BLOCKS) * 512 + tid;  // 32768 exact
        int f = k & 63;
        int c = (k >> 6) & 63;
        int t = k >> 12;
        K_T[f * 512 + t * 64 + c] = f2bf(Kmat[k]);
    }
}

// ---------------------------------------------------------------------------
// permfix (R11 proven code): block = one bin (256 nodes). The continuous
// ent2 base is a 196-element reduce of bincur. (1) LDS 256-hist over the
// bin's padded ent window + scan -> node starts (writes global start_g,
// CONTINUOUS positions); (2) scatter entries to node-sorted slots as u32
// {rel(13b)<<16 | in(16b)} where rel = i - b*CAP indexes the PADDED binw
// window. Writes block-exclusive -> L2-merged.
// ---------------------------------------------------------------------------
__global__ __launch_bounds__(512) void permfix_kernel(const int* __restrict__ bincur,
                                                      const unsigned* __restrict__ ent,
                                                      int* __restrict__ start_g,
                                                      unsigned* __restrict__ ent2) {
    __shared__ int sh[768];
    const int tid = threadIdx.x;
    const int b   = blockIdx.x;

    // base2 = sum of bincur[0..b)  (b <= 195 < 512)
    sh[tid] = (tid < b) ? bincur[tid] : 0;
    __syncthreads();
#pragma unroll
    for (int off = 256; off >= 1; off >>= 1) {
        if (tid < off) sh[tid] += sh[tid + off];
        __syncthreads();
    }
    const int base2 = sh[0];
    const int cnt   = min(bincur[b], CAP);
    const int W0p   = b * CAP;
    __syncthreads();

    int* hist = sh;        // 256
    int* sc   = sh + 256;  // 256
    int* cur  = sh + 512;  // 256

    if (tid < 256) hist[tid] = 0;
    __syncthreads();
    for (int i = W0p + tid; i < W0p + cnt; i += 512)
        atomicAdd(&hist[ent[i] >> 16], 1);
    __syncthreads();

    if (tid < 256) sc[tid] = hist[tid];
    __syncthreads();
    for (int off = 1; off < 256; off <<= 1) {
        int x = 0;
        if (tid < 256 && tid >= off) x = sc[tid - off];
        __syncthreads();
        if (tid < 256 && tid >= off) sc[tid] += x;
        __syncthreads();
    }
    if (tid < 256) {
        int s = base2 + sc[tid] - hist[tid];  // exclusive, continuous
        int g = b * 256 + tid;
        if (g < N_OUT) start_g[g] = s;
        cur[tid] = s;
    }
    if (b == NBIN_S - 1 && tid == 0) start_g[N_OUT] = E;
    __syncthreads();

    for (int i = W0p + tid; i < W0p + cnt; i += 512) {
        unsigned u = ent[i];
        int loc = (int)(u >> 16);
        int pos = atomicAdd(&cur[loc], 1);
        ent2[pos] = ((unsigned)(i - W0p) << 16) | (u & 0xFFFFu);  // rel | in
    }
}

// ---------------------------------------------------------------------------
// Aggregate (R11 proven code, 55us): block = 4 waves = 16 output nodes,
// bijective XCD swizzle (the 16 blocks of each 256-node bin share one XCD
// -> the bin's ~160KB binw window is fetched ~once into that XCD's L2).
// ---------------------------------------------------------------------------
__global__ __launch_bounds__(256) void aggregate_kernel(const unsigned short* __restrict__ nf_bf,
                                                        const unsigned short* __restrict__ K_T,
                                                        const int* __restrict__ start,
                                                        const unsigned* __restrict__ ent2,
                                                        const float* __restrict__ binw,
                                                        const float* __restrict__ bias,
                                                        float* __restrict__ out) {
    __shared__ unsigned short A_lds[16][520];  // +8 pad

    // bijective XCD swizzle: 3125 blocks over 8 XCDs (q=390, r=5)
    constexpr int NWG = N_OUT / 16;  // 3125
    constexpr int Q = NWG / 8, R = NWG % 8;
    const int xc = blockIdx.x & 7;
    const int sl = blockIdx.x >> 3;
    const int orig = (xc < R ? xc * (Q + 1) : R * (Q + 1) + (xc - R) * Q) + sl;

    const int wave = threadIdx.x >> 6;
    const int lane = threadIdx.x & 63;
    const int node_base = orig * 16;
    const int Wbase = (orig >> 4) * CAP;  // bin's padded binw window base

    // ---- Phase 1: segment aggregation ----
    for (int q = 0; q < 4; ++q) {
        const int m = wave * 4 + q;
        const int o = node_base + m;
        const int s0 = __builtin_amdgcn_readfirstlane(start[o]);
        const int s1 = __builtin_amdgcn_readfirstlane(start[o + 1]);

        float acc[8] = {0.f, 0.f, 0.f, 0.f, 0.f, 0.f, 0.f, 0.f};

        for (int base = s0; base < s1; base += 64) {
            const int cnt = min(64, s1 - base);
            // coalesced preload of this chunk's packed {rel, in} entries
            int vv = (base + lane < s1) ? (int)ent2[base + lane] : 0;

            int j = 0;
            for (; j + 4 <= cnt; j += 4) {
                const int v0 = __builtin_amdgcn_readlane(vv, j + 0);
                const int v1 = __builtin_amdgcn_readlane(vv, j + 1);
                const int v2 = __builtin_amdgcn_readlane(vv, j + 2);
                const int v3 = __builtin_amdgcn_readlane(vv, j + 3);
                // 4 independent 128 B gathers in flight
                float x0 = bf2f(nf_bf[(size_t)(v0 & 0xFFFF) * 64 + lane]);
                float x1 = bf2f(nf_bf[(size_t)(v1 & 0xFFFF) * 64 + lane]);
                float x2 = bf2f(nf_bf[(size_t)(v2 & 0xFFFF) * 64 + lane]);
                float x3 = bf2f(nf_bf[(size_t)(v3 & 0xFFFF) * 64 + lane]);
                // wave-uniform scalar fp32 weight loads (bin-local window)
                const float* w0 = binw + (size_t)(Wbase + (((unsigned)v0) >> 16)) * 8;
                const float* w1 = binw + (size_t)(Wbase + (((unsigned)v1) >> 16)) * 8;
                const float* w2 = binw + (size_t)(Wbase + (((unsigned)v2) >> 16)) * 8;
                const float* w3 = binw + (size_t)(Wbase + (((unsigned)v3) >> 16)) * 8;
#pragma unroll
                for (int t = 0; t < T; ++t) {
                    acc[t] += w0[t] * x0;
                    acc[t] += w1[t] * x1;
                    acc[t] += w2[t] * x2;
                    acc[t] += w3[t] * x3;
                }
            }
            for (; j < cnt; ++j) {
                const int v0 = __builtin_amdgcn_readlane(vv, j);
                float x0 = bf2f(nf_bf[(size_t)(v0 & 0xFFFF) * 64 + lane]);
                const float* w0 = binw + (size_t)(Wbase + (((unsigned)v0) >> 16)) * 8;
#pragma unroll
                for (int t = 0; t < T; ++t) acc[t] += w0[t] * x0;
            }
        }

#pragma unroll
        for (int t = 0; t < T; ++t) A_lds[m][t * 64 + lane] = f2bf(acc[t]);
    }
    __syncthreads();

    // ---- Phase 2: MFMA epilogue; wave handles f-tile [wave*16, wave*16+16) ----
    const int mrow = lane & 15;
    const int kb   = lane >> 4;
    const int fcol = wave * 16 + mrow;

    f32x4 acc4 = {0.f, 0.f, 0.f, 0.f};
#pragma unroll
    for (int s = 0; s < 16; ++s) {
        const int k0 = s * 32 + kb * 8;
        short8 a = *(const short8*)&A_lds[mrow][k0];
        short8 b = *(const short8*)(K_T + (size_t)fcol * 512 + k0);
        acc4 = __builtin_amdgcn_mfma_f32_16x16x32_bf16(a, b, acc4, 0, 0, 0);
    }

    const float bv = bias[fcol];
#pragma unroll
    for (int r = 0; r < 4; ++r) {
        const int m = kb * 4 + r;
        out[(size_t)(node_base + m) * F + fcol] = acc4[r] + bv;
    }
}

// ---------------------------------------------------------------------------
extern "C" void kernel_launch(void* const* d_in, const int* in_sizes, int n_in,
                              void* d_out, int out_size, void* d_ws, size_t ws_size,
                              hipStream_t stream) {
    const float* nf   = (const float*)d_in[0];  // (N_IN, C)
    const float* ef   = (const float*)d_in[1];  // (T, E)
    const int*   idx  = (const int*)d_in[2];    // (E, 2) int32 on device
    const float* Kmat = (const float*)d_in[3];  // (T, C, F)
    const float* bias = (const float*)d_in[4];  // (F,)
    float*       out  = (float*)d_out;          // (N_OUT, F)

    char* ws = (char*)d_ws;
    unsigned short* nf_bf  = (unsigned short*)(ws + OFF_NFBF);
    unsigned short* K_T    = (unsigned short*)(ws + OFF_KT);
    int*            bincur = (int*)(ws + OFF_BCUR);
    int*            start  = (int*)(ws + OFF_START);
    unsigned*       ent    = (unsigned*)(ws + OFF_ENT);
    unsigned*       ent2   = (unsigned*)(ws + OFF_ENT2);
    float*          binw   = (float*)(ws + OFF_BINW);

    hipMemsetAsync(bincur, 0, NBIN_S * sizeof(int), stream);
    fused_prep_kernel<<<BS_BLOCKS + NF_BLOCKS + KT_BLOCKS, 512, 0, stream>>>(
        nf, Kmat, ef, idx, nf_bf, K_T, bincur, ent, binw);
    permfix_kernel<<<NBIN_S, 512, 0, stream>>>(bincur, ent, start, ent2);
    aggregate_kernel<<<N_OUT / 16, 256, 0, stream>>>(
        nf_bf, K_T, start, ent2, binw, bias, out);
}